// Round 6
// baseline (133.784 us; speedup 1.0000x reference)
//
#include <hip/hip_runtime.h>

// RoiAlign (tf.image.crop_and_resize, bilinear, extrapolation=0)
// fm [8,64,64,256] f32, boxes [8,1000,4] f32, P=7 -> out [8,1000,7,7,256] f32.
//
// Mapping: 1 wave per BOX (49 positions). Lane i covers channels [4i,4i+4)
// as float4 (64 lanes * 16B = 1KB per tap load / store).
// Box-per-wave amortization: box load + all x-coordinate state (shared by the
// 7 py-rows) computed ONCE; per py-row: y-math + 28 tap loads + 7 lerp/stores.
// Store stream is 49KB contiguous NT per wave.
//
// XCD-batch partitioning: b = blockIdx.x % 8 -> each XCD serves one batch;
// that batch's fm slice (4MB) == one XCD L2 (round-2: +8%).
// NT stores keep the 401MB write stream from evicting fm from L2
// (round-3: 134 -> 96.6 us). Row-amortization round-5: 94.4 -> 81.8 us.

#define BATCH 8
#define FH 64
#define FW 64
#define FC 256
#define NBOX 1000
#define PP 7
#define POS_PER_BATCH (NBOX * PP * PP)   // 49000

typedef __attribute__((ext_vector_type(4))) float f32x4;

__global__ __launch_bounds__(256, 3) void roi_align_kernel(
    const float* __restrict__ fm,
    const float* __restrict__ boxes,
    float* __restrict__ out)
{
    const int lane = threadIdx.x & 63;
    const int wib  = threadIdx.x >> 6;          // wave in block: 0..3

    const int b = blockIdx.x & 7;               // batch == XCD (round-robin)
    const int n = (blockIdx.x >> 3) * 4 + wib;  // box 0..999

    const int c4 = lane * 4;                    // channel offset for this lane
    const float* __restrict__ fmb = fm + (size_t)b * FH * FW * FC + c4;

    // Box: [y1,x1,y2,x2] normalized (wave-uniform)
    const float* bx = boxes + (b * NBOX + n) * 4;
    const float y1 = bx[0];
    const float x1 = bx[1];
    const float y2 = bx[2];
    const float x2 = bx[3];

    // x-state: ONCE per box (shared by all 7 py rows).
    // Reference: xs = x1*(w-1) + t*((x2-x1)*(w-1)/(P-1))  (exact order)
    const float xbase = x1 * (float)(FW - 1);
    const float xstep = (x2 - x1) * (float)(FW - 1) / (float)(PP - 1);

    int   xo_lo[PP], xo_hi[PP];     // element offsets x*FC
    float wxv[PP], vxm[PP];
    #pragma unroll
    for (int px = 0; px < PP; ++px) {
        const float xc = xbase + (float)px * xstep;
        const float xlo_f = floorf(xc);
        wxv[px] = xc - xlo_f;
        int x_lo = (int)xlo_f;
        int x_hi = x_lo + 1;
        x_lo = min(max(x_lo, 0), FW - 1);
        x_hi = min(max(x_hi, 0), FW - 1);
        xo_lo[px] = x_lo * FC;
        xo_hi[px] = x_hi * FC;
        vxm[px] = ((xc >= 0.0f) && (xc <= (float)(FW - 1))) ? 1.0f : 0.0f;
    }

    const float ystep = (y2 - y1) * (float)(FH - 1) / (float)(PP - 1);
    const float ybase = y1 * (float)(FH - 1);

    float* pob = out + ((size_t)b * NBOX + n) * (PP * PP) * FC + c4;

    for (int py = 0; py < PP; ++py) {
        // Reference: ys = y1*(h-1) + t*((y2-y1)*(h-1)/(P-1))  (exact order)
        const float yc = ybase + (float)py * ystep;
        const float ylo_f = floorf(yc);
        const float wy    = yc - ylo_f;
        int y_lo = (int)ylo_f;
        int y_hi = y_lo + 1;
        y_lo = min(max(y_lo, 0), FH - 1);
        y_hi = min(max(y_hi, 0), FH - 1);
        const float vym = ((yc >= 0.0f) && (yc <= (float)(FH - 1))) ? 1.0f : 0.0f;

        const float* rlo = fmb + (size_t)(y_lo * FW) * FC;
        const float* rhi = fmb + (size_t)(y_hi * FW) * FC;

        // Issue all 28 tap loads for this row
        float4 v00[PP], v01[PP], v10[PP], v11[PP];
        #pragma unroll
        for (int px = 0; px < PP; ++px) {
            v00[px] = *(const float4*)(rlo + xo_lo[px]);
            v01[px] = *(const float4*)(rlo + xo_hi[px]);
            v10[px] = *(const float4*)(rhi + xo_lo[px]);
            v11[px] = *(const float4*)(rhi + xo_hi[px]);
        }

        // Interpolate + NT store (7 contiguous 1KB stores)
        float* po = pob + (size_t)(py * PP) * FC;
        #pragma unroll
        for (int px = 0; px < PP; ++px) {
            const float wx = wxv[px];
            const float vm = vym * vxm[px];
            float4 top, bot;
            f32x4 r;
            top.x = v00[px].x + (v01[px].x - v00[px].x) * wx;
            top.y = v00[px].y + (v01[px].y - v00[px].y) * wx;
            top.z = v00[px].z + (v01[px].z - v00[px].z) * wx;
            top.w = v00[px].w + (v01[px].w - v00[px].w) * wx;
            bot.x = v10[px].x + (v11[px].x - v10[px].x) * wx;
            bot.y = v10[px].y + (v11[px].y - v10[px].y) * wx;
            bot.z = v10[px].z + (v11[px].z - v10[px].z) * wx;
            bot.w = v10[px].w + (v11[px].w - v10[px].w) * wx;
            r.x = (top.x + (bot.x - top.x) * wy) * vm;
            r.y = (top.y + (bot.y - top.y) * wy) * vm;
            r.z = (top.z + (bot.z - top.z) * wy) * vm;
            r.w = (top.w + (bot.w - top.w) * wy) * vm;

            __builtin_nontemporal_store(r, (f32x4*)(po + (size_t)px * FC));
        }
    }
}

extern "C" void kernel_launch(void* const* d_in, const int* in_sizes, int n_in,
                              void* d_out, int out_size, void* d_ws, size_t ws_size,
                              hipStream_t stream) {
    const float* fm    = (const float*)d_in[0];
    const float* boxes = (const float*)d_in[1];
    float* out = (float*)d_out;

    const int threads = 256;                     // 4 waves/block, 1 box/wave
    const int blocks  = BATCH * (NBOX / 4);      // 8 * 250 = 2000

    roi_align_kernel<<<blocks, threads, 0, stream>>>(fm, boxes, out);
}

// Round 7
// 83.516 us; speedup vs baseline: 1.6019x; 1.6019x over previous
//
#include <hip/hip_runtime.h>

// RoiAlign (tf.image.crop_and_resize, bilinear, extrapolation=0)
// fm [8,64,64,256] f32, boxes [8,1000,4] f32, P=7 -> out [8,1000,7,7,256] f32.
//
// Structure (round-5 winner, 81.8us) + bf16 tap staging (round-7):
//  - Pre-pass converts fm f32 -> bf16 into d_ws (16.7MB, ~7us streaming).
//  - Main: 1 wave per (box, py) row -> 7 positions. Lane i -> channels
//    [4i,4i+4). Taps read as ushort4 (512B/wave/tap, halves the L2 random-
//    gather stream that co-limits with the 401MB write stream). Lerp in f32.
//  - XCD-batch partitioning: b = blockIdx.x % 8 (each batch fm = 4MB = 1 L2).
//  - NT stores: write stream must not evict fm from L2 (134 -> 96.6us).
// Round-6 lesson: box-per-wave (8K waves) starves latency hiding - keep 56K.

#define BATCH 8
#define FH 64
#define FW 64
#define FC 256
#define NBOX 1000
#define PP 7
#define POS_PER_BATCH (NBOX * PP * PP)   // 49000
#define ROWS_PER_BATCH (NBOX * PP)       // 7000
#define FM_ELEMS (BATCH * FH * FW * FC)  // 8388608

typedef __attribute__((ext_vector_type(4))) float f32x4;

__device__ __forceinline__ float bf2f(unsigned short u) {
    union { unsigned int i; float f; } c;
    c.i = ((unsigned int)u) << 16;
    return c.f;
}

__device__ __forceinline__ unsigned short f2bf(float x) {
    unsigned int b = __float_as_uint(x);
    b = (b + 0x7fffu + ((b >> 16) & 1u)) >> 16;   // round-to-nearest-even
    return (unsigned short)b;
}

// ---------------- pre-pass: fm f32 -> bf16 in workspace ----------------
__global__ __launch_bounds__(256) void fm_convert_kernel(
    const float4* __restrict__ in, ushort4* __restrict__ out, int n4)
{
    int i = blockIdx.x * blockDim.x + threadIdx.x;
    const int stride = gridDim.x * blockDim.x;
    for (; i < n4; i += stride) {
        const float4 v = in[i];
        ushort4 o;
        o.x = f2bf(v.x); o.y = f2bf(v.y); o.z = f2bf(v.z); o.w = f2bf(v.w);
        out[i] = o;
    }
}

// ---------------- main kernel (bf16 taps) ----------------
__global__ __launch_bounds__(256, 4) void roi_align_bf16_kernel(
    const ushort* __restrict__ fmb16,
    const float* __restrict__ boxes,
    float* __restrict__ out)
{
    const int lane = threadIdx.x & 63;
    const int wib  = threadIdx.x >> 6;          // wave in block: 0..3

    const int b    = blockIdx.x & 7;            // batch == XCD (round-robin)
    const int lblk = blockIdx.x >> 3;           // 0..1749
    const int row  = lblk * 4 + wib;            // 0..6999  (= n*7 + py)

    const int n  = row / PP;
    const int py = row % PP;

    const int c4 = lane * 4;                    // channel offset for this lane
    const ushort* __restrict__ fmb = fmb16 + (size_t)b * FH * FW * FC + c4;

    // Box: [y1,x1,y2,x2] normalized (wave-uniform)
    const float* bx = boxes + (b * NBOX + n) * 4;
    const float y1 = bx[0];
    const float x1 = bx[1];
    const float y2 = bx[2];
    const float x2 = bx[3];

    // y: once per row. Reference: ys = y1*(h-1) + t*((y2-y1)*(h-1)/(P-1))
    const float yc = y1 * (float)(FH - 1)
                   + (float)py * ((y2 - y1) * (float)(FH - 1) / (float)(PP - 1));
    const float ylo_f = floorf(yc);
    const float wy    = yc - ylo_f;
    int y_lo = (int)ylo_f;
    int y_hi = y_lo + 1;
    y_lo = min(max(y_lo, 0), FH - 1);
    y_hi = min(max(y_hi, 0), FH - 1);
    const bool vy = (yc >= 0.0f) && (yc <= (float)(FH - 1));

    const float xstep = (x2 - x1) * (float)(FW - 1) / (float)(PP - 1);
    const float xbase = x1 * (float)(FW - 1);

    const ushort* rlo = fmb + (size_t)(y_lo * FW) * FC;
    const ushort* rhi = fmb + (size_t)(y_hi * FW) * FC;

    float wxv[PP], vmask[PP];
    ushort4 v00[PP], v01[PP], v10[PP], v11[PP];

    // Phase 1: x-coords + issue all 28 tap loads (8B/lane, 512B/wave each)
    #pragma unroll
    for (int px = 0; px < PP; ++px) {
        const float xc = xbase + (float)px * xstep;   // exact reference order
        const float xlo_f = floorf(xc);
        wxv[px] = xc - xlo_f;
        int x_lo = (int)xlo_f;
        int x_hi = x_lo + 1;
        x_lo = min(max(x_lo, 0), FW - 1);
        x_hi = min(max(x_hi, 0), FW - 1);
        const bool vx = (xc >= 0.0f) && (xc <= (float)(FW - 1));
        vmask[px] = (vy && vx) ? 1.0f : 0.0f;

        v00[px] = *(const ushort4*)(rlo + (size_t)x_lo * FC);
        v01[px] = *(const ushort4*)(rlo + (size_t)x_hi * FC);
        v10[px] = *(const ushort4*)(rhi + (size_t)x_lo * FC);
        v11[px] = *(const ushort4*)(rhi + (size_t)x_hi * FC);
    }

    // Phase 2: convert + interpolate in f32 + NT store (7 contiguous 1KB)
    float* po = out + ((size_t)b * POS_PER_BATCH + (size_t)row * PP) * FC + c4;
    #pragma unroll
    for (int px = 0; px < PP; ++px) {
        const float wx = wxv[px], vm = vmask[px];
        const float a00x = bf2f(v00[px].x), a01x = bf2f(v01[px].x);
        const float a00y = bf2f(v00[px].y), a01y = bf2f(v01[px].y);
        const float a00z = bf2f(v00[px].z), a01z = bf2f(v01[px].z);
        const float a00w = bf2f(v00[px].w), a01w = bf2f(v01[px].w);
        const float a10x = bf2f(v10[px].x), a11x = bf2f(v11[px].x);
        const float a10y = bf2f(v10[px].y), a11y = bf2f(v11[px].y);
        const float a10z = bf2f(v10[px].z), a11z = bf2f(v11[px].z);
        const float a10w = bf2f(v10[px].w), a11w = bf2f(v11[px].w);

        float4 top, bot;
        f32x4 r;
        top.x = a00x + (a01x - a00x) * wx;
        top.y = a00y + (a01y - a00y) * wx;
        top.z = a00z + (a01z - a00z) * wx;
        top.w = a00w + (a01w - a00w) * wx;
        bot.x = a10x + (a11x - a10x) * wx;
        bot.y = a10y + (a11y - a10y) * wx;
        bot.z = a10z + (a11z - a10z) * wx;
        bot.w = a10w + (a11w - a10w) * wx;
        r.x = (top.x + (bot.x - top.x) * wy) * vm;
        r.y = (top.y + (bot.y - top.y) * wy) * vm;
        r.z = (top.z + (bot.z - top.z) * wy) * vm;
        r.w = (top.w + (bot.w - top.w) * wy) * vm;

        __builtin_nontemporal_store(r, (f32x4*)(po + (size_t)px * FC));
    }
}

// ---------------- fallback (f32 taps, round-5 kernel) ----------------
__global__ __launch_bounds__(256, 3) void roi_align_f32_kernel(
    const float* __restrict__ fm,
    const float* __restrict__ boxes,
    float* __restrict__ out)
{
    const int lane = threadIdx.x & 63;
    const int wib  = threadIdx.x >> 6;
    const int b    = blockIdx.x & 7;
    const int lblk = blockIdx.x >> 3;
    const int row  = lblk * 4 + wib;
    const int n  = row / PP;
    const int py = row % PP;
    const int c4 = lane * 4;
    const float* __restrict__ fmb = fm + (size_t)b * FH * FW * FC + c4;

    const float* bx = boxes + (b * NBOX + n) * 4;
    const float y1 = bx[0], x1 = bx[1], y2 = bx[2], x2 = bx[3];

    const float yc = y1 * (float)(FH - 1)
                   + (float)py * ((y2 - y1) * (float)(FH - 1) / (float)(PP - 1));
    const float ylo_f = floorf(yc);
    const float wy    = yc - ylo_f;
    int y_lo = (int)ylo_f;
    int y_hi = y_lo + 1;
    y_lo = min(max(y_lo, 0), FH - 1);
    y_hi = min(max(y_hi, 0), FH - 1);
    const bool vy = (yc >= 0.0f) && (yc <= (float)(FH - 1));

    const float xstep = (x2 - x1) * (float)(FW - 1) / (float)(PP - 1);
    const float xbase = x1 * (float)(FW - 1);
    const float* rlo = fmb + (size_t)(y_lo * FW) * FC;
    const float* rhi = fmb + (size_t)(y_hi * FW) * FC;

    float wxv[PP], vmask[PP];
    float4 v00[PP], v01[PP], v10[PP], v11[PP];
    #pragma unroll
    for (int px = 0; px < PP; ++px) {
        const float xc = xbase + (float)px * xstep;
        const float xlo_f = floorf(xc);
        wxv[px] = xc - xlo_f;
        int x_lo = (int)xlo_f;
        int x_hi = x_lo + 1;
        x_lo = min(max(x_lo, 0), FW - 1);
        x_hi = min(max(x_hi, 0), FW - 1);
        const bool vx = (xc >= 0.0f) && (xc <= (float)(FW - 1));
        vmask[px] = (vy && vx) ? 1.0f : 0.0f;
        v00[px] = *(const float4*)(rlo + (size_t)x_lo * FC);
        v01[px] = *(const float4*)(rlo + (size_t)x_hi * FC);
        v10[px] = *(const float4*)(rhi + (size_t)x_lo * FC);
        v11[px] = *(const float4*)(rhi + (size_t)x_hi * FC);
    }
    float* po = out + ((size_t)b * POS_PER_BATCH + (size_t)row * PP) * FC + c4;
    #pragma unroll
    for (int px = 0; px < PP; ++px) {
        const float wx = wxv[px], vm = vmask[px];
        float4 top, bot;
        f32x4 r;
        top.x = v00[px].x + (v01[px].x - v00[px].x) * wx;
        top.y = v00[px].y + (v01[px].y - v00[px].y) * wx;
        top.z = v00[px].z + (v01[px].z - v00[px].z) * wx;
        top.w = v00[px].w + (v01[px].w - v00[px].w) * wx;
        bot.x = v10[px].x + (v11[px].x - v10[px].x) * wx;
        bot.y = v10[px].y + (v11[px].y - v10[px].y) * wx;
        bot.z = v10[px].z + (v11[px].z - v10[px].z) * wx;
        bot.w = v10[px].w + (v11[px].w - v10[px].w) * wx;
        r.x = (top.x + (bot.x - top.x) * wy) * vm;
        r.y = (top.y + (bot.y - top.y) * wy) * vm;
        r.z = (top.z + (bot.z - top.z) * wy) * vm;
        r.w = (top.w + (bot.w - top.w) * wy) * vm;
        __builtin_nontemporal_store(r, (f32x4*)(po + (size_t)px * FC));
    }
}

extern "C" void kernel_launch(void* const* d_in, const int* in_sizes, int n_in,
                              void* d_out, int out_size, void* d_ws, size_t ws_size,
                              hipStream_t stream) {
    const float* fm    = (const float*)d_in[0];
    const float* boxes = (const float*)d_in[1];
    float* out = (float*)d_out;

    const int threads = 256;
    const int blocks  = BATCH * (ROWS_PER_BATCH / 4);   // 8 * 1750 = 14000

    const size_t need = (size_t)FM_ELEMS * sizeof(unsigned short); // 16.7MB
    if (ws_size >= need) {
        ushort* fmb16 = (ushort*)d_ws;
        fm_convert_kernel<<<2048, threads, 0, stream>>>(
            (const float4*)fm, (ushort4*)fmb16, FM_ELEMS / 4);
        roi_align_bf16_kernel<<<blocks, threads, 0, stream>>>(fmb16, boxes, out);
    } else {
        roi_align_f32_kernel<<<blocks, threads, 0, stream>>>(fm, boxes, out);
    }
}

// Round 8
// 82.343 us; speedup vs baseline: 1.6247x; 1.0143x over previous
//
#include <hip/hip_runtime.h>

// RoiAlign (tf.image.crop_and_resize, bilinear, extrapolation=0)
// fm [8,64,64,256] f32, boxes [8,1000,4] f32, P=7 -> out [8,1000,7,7,256] f32.
//
// Round-8 structure: row-per-wave (round-5 winner) + 2-deep px software
// pipeline. Instead of 28 tap loads live at once (~150 VGPR -> 3 waves/SIMD),
// keep only 2 positions' taps live (8 float4): issue loads for px+1, then
// lerp+store px. sched_barrier(0) between stages stops the compiler from
// hoisting all loads to the top. launch_bounds(256,5) -> <=102 VGPR ->
// 20 waves/CU, so other waves' VALU hides vmcnt waits.
//
// Kept from earlier rounds:
//  - 1 wave per (box,py) row; lane i -> channels [4i,4i+4) as float4
//    (64*16B = 1KB coalesced per tap load / store).           (r5: -13%)
//  - XCD-batch partitioning b = blockIdx.x % 8: each batch fm slice = 4MB
//    = one XCD L2.                                            (r2: -8%)
//  - NT stores: 401MB write stream must not evict fm from L2. (r3: -28%)
// Lessons: box-per-wave starves wave count (r6); bf16 staging neutral (r7).

#define BATCH 8
#define FH 64
#define FW 64
#define FC 256
#define NBOX 1000
#define PP 7
#define POS_PER_BATCH (NBOX * PP * PP)   // 49000
#define ROWS_PER_BATCH (NBOX * PP)       // 7000

typedef __attribute__((ext_vector_type(4))) float f32x4;

__global__ __launch_bounds__(256, 5) void roi_align_kernel(
    const float* __restrict__ fm,
    const float* __restrict__ boxes,
    float* __restrict__ out)
{
    const int lane = threadIdx.x & 63;
    const int wib  = threadIdx.x >> 6;          // wave in block: 0..3

    const int b    = blockIdx.x & 7;            // batch == XCD (round-robin)
    const int lblk = blockIdx.x >> 3;           // 0..1749
    const int row  = lblk * 4 + wib;            // 0..6999  (= n*7 + py)

    const int n  = row / PP;
    const int py = row % PP;

    const int c4 = lane * 4;                    // channel offset for this lane
    const float* __restrict__ fmb = fm + (size_t)b * FH * FW * FC + c4;

    // Box: [y1,x1,y2,x2] normalized (wave-uniform)
    const float* bx = boxes + (b * NBOX + n) * 4;
    const float y1 = bx[0];
    const float x1 = bx[1];
    const float y2 = bx[2];
    const float x2 = bx[3];

    // y: once per row. Reference: ys = y1*(h-1) + t*((y2-y1)*(h-1)/(P-1))
    const float yc = y1 * (float)(FH - 1)
                   + (float)py * ((y2 - y1) * (float)(FH - 1) / (float)(PP - 1));
    const float ylo_f = floorf(yc);
    const float wy    = yc - ylo_f;
    int y_lo = (int)ylo_f;
    int y_hi = y_lo + 1;
    y_lo = min(max(y_lo, 0), FH - 1);
    y_hi = min(max(y_hi, 0), FH - 1);
    const bool vy = (yc >= 0.0f) && (yc <= (float)(FH - 1));

    const float xstep = (x2 - x1) * (float)(FW - 1) / (float)(PP - 1);
    const float xbase = x1 * (float)(FW - 1);

    const float* rlo = fmb + (size_t)(y_lo * FW) * FC;
    const float* rhi = fmb + (size_t)(y_hi * FW) * FC;

    float* po = out + ((size_t)b * POS_PER_BATCH + (size_t)row * PP) * FC + c4;

    // 2-slot pipeline state (statically indexed under full unroll)
    float4 t00[2], t01[2], t10[2], t11[2];
    float  twx[2], tvm[2];

    // ---- prologue: issue loads for px=0 ----
    {
        const float xc = xbase;                    // px=0: exact reference order
        const float xlo_f = floorf(xc);
        twx[0] = xc - xlo_f;
        int x_lo = (int)xlo_f;
        int x_hi = x_lo + 1;
        x_lo = min(max(x_lo, 0), FW - 1);
        x_hi = min(max(x_hi, 0), FW - 1);
        const bool vx = (xc >= 0.0f) && (xc <= (float)(FW - 1));
        tvm[0] = (vy && vx) ? 1.0f : 0.0f;
        t00[0] = *(const float4*)(rlo + (size_t)x_lo * FC);
        t01[0] = *(const float4*)(rlo + (size_t)x_hi * FC);
        t10[0] = *(const float4*)(rhi + (size_t)x_lo * FC);
        t11[0] = *(const float4*)(rhi + (size_t)x_hi * FC);
    }

    #pragma unroll
    for (int px = 1; px < PP; ++px) {
        const int cur = px & 1;
        const int prv = cur ^ 1;

        // stage: x-math + issue 4 tap loads for px
        const float xc = xbase + (float)px * xstep;   // exact reference order
        const float xlo_f = floorf(xc);
        twx[cur] = xc - xlo_f;
        int x_lo = (int)xlo_f;
        int x_hi = x_lo + 1;
        x_lo = min(max(x_lo, 0), FW - 1);
        x_hi = min(max(x_hi, 0), FW - 1);
        const bool vx = (xc >= 0.0f) && (xc <= (float)(FW - 1));
        tvm[cur] = (vy && vx) ? 1.0f : 0.0f;
        t00[cur] = *(const float4*)(rlo + (size_t)x_lo * FC);
        t01[cur] = *(const float4*)(rlo + (size_t)x_hi * FC);
        t10[cur] = *(const float4*)(rhi + (size_t)x_lo * FC);
        t11[cur] = *(const float4*)(rhi + (size_t)x_hi * FC);

        __builtin_amdgcn_sched_barrier(0);   // pin pipeline stage boundary

        // compute + NT store for px-1
        {
            const float wx = twx[prv], vm = tvm[prv];
            float4 top, bot;
            f32x4 r;
            top.x = t00[prv].x + (t01[prv].x - t00[prv].x) * wx;
            top.y = t00[prv].y + (t01[prv].y - t00[prv].y) * wx;
            top.z = t00[prv].z + (t01[prv].z - t00[prv].z) * wx;
            top.w = t00[prv].w + (t01[prv].w - t00[prv].w) * wx;
            bot.x = t10[prv].x + (t11[prv].x - t10[prv].x) * wx;
            bot.y = t10[prv].y + (t11[prv].y - t10[prv].y) * wx;
            bot.z = t10[prv].z + (t11[prv].z - t10[prv].z) * wx;
            bot.w = t10[prv].w + (t11[prv].w - t10[prv].w) * wx;
            r.x = (top.x + (bot.x - top.x) * wy) * vm;
            r.y = (top.y + (bot.y - top.y) * wy) * vm;
            r.z = (top.z + (bot.z - top.z) * wy) * vm;
            r.w = (top.w + (bot.w - top.w) * wy) * vm;
            __builtin_nontemporal_store(r, (f32x4*)(po + (size_t)(px - 1) * FC));
        }
        __builtin_amdgcn_sched_barrier(0);   // pin end of iteration
    }

    // ---- epilogue: compute + store px=6 (slot (PP-1)&1 == 0) ----
    {
        const int prv = (PP - 1) & 1;
        const float wx = twx[prv], vm = tvm[prv];
        float4 top, bot;
        f32x4 r;
        top.x = t00[prv].x + (t01[prv].x - t00[prv].x) * wx;
        top.y = t00[prv].y + (t01[prv].y - t00[prv].y) * wx;
        top.z = t00[prv].z + (t01[prv].z - t00[prv].z) * wx;
        top.w = t00[prv].w + (t01[prv].w - t00[prv].w) * wx;
        bot.x = t10[prv].x + (t11[prv].x - t10[prv].x) * wx;
        bot.y = t10[prv].y + (t11[prv].y - t10[prv].y) * wx;
        bot.z = t10[prv].z + (t11[prv].z - t10[prv].z) * wx;
        bot.w = t10[prv].w + (t11[prv].w - t10[prv].w) * wx;
        r.x = (top.x + (bot.x - top.x) * wy) * vm;
        r.y = (top.y + (bot.y - top.y) * wy) * vm;
        r.z = (top.z + (bot.z - top.z) * wy) * vm;
        r.w = (top.w + (bot.w - top.w) * wy) * vm;
        __builtin_nontemporal_store(r, (f32x4*)(po + (size_t)(PP - 1) * FC));
    }
}

extern "C" void kernel_launch(void* const* d_in, const int* in_sizes, int n_in,
                              void* d_out, int out_size, void* d_ws, size_t ws_size,
                              hipStream_t stream) {
    const float* fm    = (const float*)d_in[0];
    const float* boxes = (const float*)d_in[1];
    float* out = (float*)d_out;

    const int threads = 256;                              // 4 waves/block
    const int blocks  = BATCH * (ROWS_PER_BATCH / 4);     // 8 * 1750 = 14000

    roi_align_kernel<<<blocks, threads, 0, stream>>>(fm, boxes, out);
}